// Round 9
// baseline (159.418 us; speedup 1.0000x reference)
//
#include <hip/hip_runtime.h>
#include <hip/hip_bf16.h>
#include <math.h>

#define Bn 8
#define Tn 2048
#define Cn 384
#define Hn 64
#define SCALE 0.051031036307982884f  // 384^-0.5

using bf16x8 = __attribute__((ext_vector_type(8))) short;  // 8 bf16 = 4 VGPRs
using f32x4  = __attribute__((ext_vector_type(4))) float;

#define MFMA(a, b, c) __builtin_amdgcn_mfma_f32_16x16x32_bf16((a), (b), (c), 0, 0, 0)

static __device__ __forceinline__ short f2bf(float f) {  // RNE fp32->bf16
  unsigned u = __float_as_uint(f);
  u += 0x7fffu + ((u >> 16) & 1u);
  return (short)(u >> 16);
}
static __device__ __forceinline__ float bf2f(short s) {
  return __uint_as_float(((unsigned)(unsigned short)s) << 16);
}

// ---------------- K0: W -> WbT (192 x 384) bf16, row n = output col ---------
__global__ __launch_bounds__(256) void wconv_kernel(
    const float* __restrict__ Wq, const float* __restrict__ Wk,
    const float* __restrict__ Wv, short* __restrict__ WbT) {
  int idx = blockIdx.x * 256 + threadIdx.x;  // n*384 + k, 73728 total
  int n = idx / 384, k = idx - n * 384;
  const float* W = (n < 64) ? Wq : (n < 128) ? Wk : Wv;
  WbT[idx] = f2bf(W[k * 64 + (n & 63)]);
}

// ---------------- K1: proj GEMM, 16-row tiles (1024 blocks, 4/CU) -----------
__global__ __launch_bounds__(256) void proj_kernel(
    const float* __restrict__ x, const short* __restrict__ WbT,
    short* __restrict__ qb, short* __restrict__ kb, short* __restrict__ vT) {
  __shared__ short xs[16][392];    // stride 392: banks 2-way (free)
  __shared__ short vtile[64][20];  // v-tile transpose bounce
  const int tid = threadIdx.x;
  const int t0 = blockIdx.x * 16;  // global row (b*2048 + t)
  const float* xb = x + (size_t)t0 * Cn;
  #pragma unroll
  for (int i = 0; i < 6; ++i) {
    int j = tid + i * 256;  // float4 index, 1536 total
    int row = j / 96, colv = (j - row * 96) * 4;
    float4 v = *(const float4*)(xb + row * Cn + colv);
    short4 s4; s4.x = f2bf(v.x); s4.y = f2bf(v.y); s4.z = f2bf(v.z); s4.w = f2bf(v.w);
    *(short4*)(&xs[row][colv]) = s4;
  }
  __syncthreads();
  const int w = tid >> 6, l15 = tid & 15, quad = (tid & 63) >> 4;
  f32x4 acc[3] = {};
  for (int ks = 0; ks < 12; ++ks) {
    bf16x8 a = *(const bf16x8*)(&xs[l15][ks * 32 + quad * 8]);
    #pragma unroll
    for (int cf = 0; cf < 3; ++cf) {
      bf16x8 bfr = *(const bf16x8*)(WbT + (size_t)(48 * w + 16 * cf + l15) * Cn + ks * 32 + quad * 8);
      acc[cf] = MFMA(a, bfr, acc[cf]);
    }
  }
  #pragma unroll
  for (int cf = 0; cf < 3; ++cf) {
    int cbase = 48 * w + 16 * cf, c = cbase + l15;
    #pragma unroll
    for (int r = 0; r < 4; ++r) {
      int row = t0 + quad * 4 + r;
      short val = f2bf(acc[cf][r]);
      if (cbase < 64)       qb[(size_t)row * Hn + c] = val;
      else if (cbase < 128) kb[(size_t)row * Hn + (c - 64)] = val;
      else                  vtile[c - 128][quad * 4 + r] = val;
    }
  }
  __syncthreads();
  const int b = t0 >> 11, t0l = t0 & 2047;
  int h = tid >> 2, tseg = (tid & 3) * 4;
  *(short4*)(vT + ((size_t)(b * Hn + h)) * Tn + t0l + tseg) =
      *(const short4*)(&vtile[h][tseg]);
}

// ---------------- K2: causal-tile score GEMM: E + column sums ---------------
// One block per (b, ti, si<=ti): 128t x 128s tile. 2x2 wave grid, each wave
// 64t x 64s = 16 accumulators, K=64 in 2 steps (32 MFMA). Fuses exp + causal
// mask + bf16 E-store + per-column partial sum (LDS reduce + 1 atomic/col).
__global__ __launch_bounds__(256) void colstats_kernel(
    const short* __restrict__ qb, const short* __restrict__ kb,
    float* __restrict__ L, short* __restrict__ Eb) {
  const int g = blockIdx.x;
  const int b = g / 136;
  const int r = g - b * 136;
  int ti = 0;
  while (((ti + 1) * (ti + 2)) >> 1 <= r) ++ti;   // triangular decode (<=15 iters)
  const int si = r - ((ti * (ti + 1)) >> 1);
  const int t0 = ti << 7, s0 = si << 7;
  const int tid = threadIdx.x, w = tid >> 6, l15 = tid & 15, quad = (tid & 63) >> 4;
  const int wt = w >> 1, ws = w & 1;
  const size_t Ebase = (size_t)b * Tn * Tn;
  __shared__ float redl[128][9];

  f32x4 acc[4][4] = {};
  #pragma unroll
  for (int ks = 0; ks < 2; ++ks) {
    bf16x8 A[4], Bf[4];
    #pragma unroll
    for (int mf = 0; mf < 4; ++mf)
      A[mf] = *(const bf16x8*)(qb + (size_t)(b * Tn + t0 + wt * 64 + mf * 16 + l15) * Hn + ks * 32 + quad * 8);
    #pragma unroll
    for (int nf = 0; nf < 4; ++nf)
      Bf[nf] = *(const bf16x8*)(kb + (size_t)(b * Tn + s0 + ws * 64 + nf * 16 + l15) * Hn + ks * 32 + quad * 8);
    #pragma unroll
    for (int mf = 0; mf < 4; ++mf)
      #pragma unroll
      for (int nf = 0; nf < 4; ++nf)
        acc[mf][nf] = MFMA(A[mf], Bf[nf], acc[mf][nf]);
  }
  const bool diag = (si == ti);
  float colsum[4] = {0.f, 0.f, 0.f, 0.f};
  #pragma unroll
  for (int mf = 0; mf < 4; ++mf) {
    const int tb = t0 + wt * 64 + mf * 16 + quad * 4;
    #pragma unroll
    for (int nf = 0; nf < 4; ++nf) {
      const int s = s0 + ws * 64 + nf * 16 + l15;
      #pragma unroll
      for (int r4 = 0; r4 < 4; ++r4) {
        float v = acc[mf][nf][r4] * SCALE;
        if (diag && s > tb + r4) v = -INFINITY;  // exp(-inf) = 0
        float ev = __expf(v);
        colsum[nf] += ev;
        Eb[Ebase + (size_t)(tb + r4) * Tn + s] = f2bf(ev);
      }
    }
  }
  #pragma unroll
  for (int nf = 0; nf < 4; ++nf)
    redl[ws * 64 + nf * 16 + l15][wt * 4 + quad] = colsum[nf];
  __syncthreads();
  if (tid < 128) {
    float ls = 0.f;
    #pragma unroll
    for (int j = 0; j < 8; ++j) ls += redl[tid][j];
    atomicAdd(&L[b * Tn + s0 + tid], ls);
  }
}

// ---------------- K3: vS[h][s] = vT[h][s] / L[s] ---------------------------
__global__ __launch_bounds__(256) void vhat_kernel(
    const short* __restrict__ vT, const float* __restrict__ L,
    short* __restrict__ vS) {
  int gid = blockIdx.x * 256 + threadIdx.x;  // 131072 threads x 8 elems
  size_t base = (size_t)gid * 8;
  int b = (int)(base >> 17), s = (int)(base & 2047);
  short4 v0 = *(const short4*)(vT + base);
  short4 v1 = *(const short4*)(vT + base + 4);
  const float* Lp = L + b * Tn + s;
  float4 L0 = *(const float4*)(Lp);
  float4 L1 = *(const float4*)(Lp + 4);
  short4 r0, r1;
  r0.x = f2bf(bf2f(v0.x) / L0.x); r0.y = f2bf(bf2f(v0.y) / L0.y);
  r0.z = f2bf(bf2f(v0.z) / L0.z); r0.w = f2bf(bf2f(v0.w) / L0.w);
  r1.x = f2bf(bf2f(v1.x) / L1.x); r1.y = f2bf(bf2f(v1.y) / L1.y);
  r1.z = f2bf(bf2f(v1.z) / L1.z); r1.w = f2bf(bf2f(v1.w) / L1.w);
  *(short4*)(vS + base) = r0;
  *(short4*)(vS + base + 4) = r1;
}

// ---------------- K4: causal-tile PV GEMM: out += E-tile . vS-tile^T --------
// One block per (b, ti, si<=ti): 128t x 64h, K=128s in 4 steps. 2x2 wave grid:
// each wave 64t x 32h = 8 accumulators, 32 MFMA. atomicAdd flush (measured
// equal to plain-store partials in R7/R8).
__global__ __launch_bounds__(256) void outg_kernel(
    const short* __restrict__ Eb, const short* __restrict__ vS,
    float* __restrict__ out) {
  const int g = blockIdx.x;
  const int b = g / 136;
  const int r = g - b * 136;
  int ti = 0;
  while (((ti + 1) * (ti + 2)) >> 1 <= r) ++ti;
  const int si = r - ((ti * (ti + 1)) >> 1);
  const int t0 = ti << 7, s0 = si << 7;
  const int tid = threadIdx.x, w = tid >> 6, l15 = tid & 15, quad = (tid & 63) >> 4;
  const int wt = w >> 1, wh = w & 1;
  const size_t Ebase = (size_t)b * Tn * Tn;
  const size_t Vbase = (size_t)b * Hn * Tn;

  f32x4 acc[4][2] = {};
  #pragma unroll
  for (int ks = 0; ks < 4; ++ks) {
    bf16x8 A[4], Bf[2];
    #pragma unroll
    for (int mf = 0; mf < 4; ++mf)
      A[mf] = *(const bf16x8*)(Eb + Ebase + (size_t)(t0 + wt * 64 + mf * 16 + l15) * Tn + s0 + ks * 32 + quad * 8);
    #pragma unroll
    for (int nf = 0; nf < 2; ++nf)
      Bf[nf] = *(const bf16x8*)(vS + Vbase + (size_t)(wh * 32 + nf * 16 + l15) * Tn + s0 + ks * 32 + quad * 8);
    #pragma unroll
    for (int mf = 0; mf < 4; ++mf)
      #pragma unroll
      for (int nf = 0; nf < 2; ++nf)
        acc[mf][nf] = MFMA(A[mf], Bf[nf], acc[mf][nf]);
  }
  #pragma unroll
  for (int mf = 0; mf < 4; ++mf) {
    const int tb = t0 + wt * 64 + mf * 16 + quad * 4;
    #pragma unroll
    for (int nf = 0; nf < 2; ++nf) {
      const int h = wh * 32 + nf * 16 + l15;
      #pragma unroll
      for (int r4 = 0; r4 < 4; ++r4)
        atomicAdd(&out[(size_t)(b * Tn + tb + r4) * Hn + h], acc[mf][nf][r4]);
    }
  }
}

extern "C" void kernel_launch(void* const* d_in, const int* in_sizes, int n_in,
                              void* d_out, int out_size, void* d_ws, size_t ws_size,
                              hipStream_t stream) {
  const float* x  = (const float*)d_in[0];
  const float* Wq = (const float*)d_in[1];
  const float* Wk = (const float*)d_in[2];
  const float* Wv = (const float*)d_in[3];
  char* ws = (char*)d_ws;                          // needs ~80 MB
  short* qb   = (short*)(ws);                      // 2 MB (T,H)
  short* kb   = (short*)(ws + 2097152);            // 2 MB (T,H)
  short* vT   = (short*)(ws + 4194304);            // 2 MB (H,T)
  short* vS   = (short*)(ws + 6291456);            // 2 MB (H,T) v/L
  short* WbT  = (short*)(ws + 8388608);            // 144 KB
  float* L    = (float*)(ws + 8536064);            // 64 KB (sum exp)
  short* Eb   = (short*)(ws + 16777216);           // 64 MB (B,T,T) bf16
  float* outp = (float*)d_out;

  hipMemsetAsync(L, 0, (size_t)Bn * Tn * 4, stream);
  hipMemsetAsync(outp, 0, (size_t)Bn * Tn * Hn * 4, stream);
  hipLaunchKernelGGL(wconv_kernel, dim3(288), dim3(256), 0, stream, Wq, Wk, Wv, WbT);
  hipLaunchKernelGGL(proj_kernel, dim3(Bn * Tn / 16), dim3(256), 0, stream, x, WbT, qb, kb, vT);
  hipLaunchKernelGGL(colstats_kernel, dim3(Bn * 136), dim3(256), 0, stream, qb, kb, L, Eb);
  hipLaunchKernelGGL(vhat_kernel, dim3(512), dim3(256), 0, stream, vT, L, vS);
  hipLaunchKernelGGL(outg_kernel, dim3(Bn * 136), dim3(256), 0, stream, Eb, vS, outp);
}

// Round 10
// 144.762 us; speedup vs baseline: 1.1012x; 1.1012x over previous
//
#include <hip/hip_runtime.h>
#include <hip/hip_bf16.h>
#include <math.h>

#define Bn 8
#define Tn 2048
#define Cn 384
#define Hn 64
#define SCALE 0.051031036307982884f  // 384^-0.5

using bf16x8 = __attribute__((ext_vector_type(8))) short;  // 8 bf16 = 4 VGPRs
using f32x4  = __attribute__((ext_vector_type(4))) float;

#define MFMA(a, b, c) __builtin_amdgcn_mfma_f32_16x16x32_bf16((a), (b), (c), 0, 0, 0)

static __device__ __forceinline__ short f2bf(float f) {  // RNE fp32->bf16
  unsigned u = __float_as_uint(f);
  u += 0x7fffu + ((u >> 16) & 1u);
  return (short)(u >> 16);
}
static __device__ __forceinline__ float bf2f(short s) {
  return __uint_as_float(((unsigned)(unsigned short)s) << 16);
}

// ---------------- K0: W -> WbT (192 x 384) bf16, row n = output col ---------
__global__ __launch_bounds__(256) void wconv_kernel(
    const float* __restrict__ Wq, const float* __restrict__ Wk,
    const float* __restrict__ Wv, short* __restrict__ WbT) {
  int idx = blockIdx.x * 256 + threadIdx.x;  // n*384 + k, 73728 total
  int n = idx / 384, k = idx - n * 384;
  const float* W = (n < 64) ? Wq : (n < 128) ? Wk : Wv;
  WbT[idx] = f2bf(W[k * 64 + (n & 63)]);
}

// ---------------- K1: proj GEMM, 16-row tiles (1024 blocks, 4/CU) -----------
__global__ __launch_bounds__(256) void proj_kernel(
    const float* __restrict__ x, const short* __restrict__ WbT,
    short* __restrict__ qb, short* __restrict__ kb, short* __restrict__ vT) {
  __shared__ short xs[16][392];    // stride 392: banks 2-way (free)
  __shared__ short vtile[64][20];  // v-tile transpose bounce
  const int tid = threadIdx.x;
  const int t0 = blockIdx.x * 16;  // global row (b*2048 + t)
  const float* xb = x + (size_t)t0 * Cn;
  #pragma unroll
  for (int i = 0; i < 6; ++i) {
    int j = tid + i * 256;  // float4 index, 1536 total
    int row = j / 96, colv = (j - row * 96) * 4;
    float4 v = *(const float4*)(xb + row * Cn + colv);
    short4 s4; s4.x = f2bf(v.x); s4.y = f2bf(v.y); s4.z = f2bf(v.z); s4.w = f2bf(v.w);
    *(short4*)(&xs[row][colv]) = s4;
  }
  __syncthreads();
  const int w = tid >> 6, l15 = tid & 15, quad = (tid & 63) >> 4;
  f32x4 acc[3] = {};
  for (int ks = 0; ks < 12; ++ks) {
    bf16x8 a = *(const bf16x8*)(&xs[l15][ks * 32 + quad * 8]);
    #pragma unroll
    for (int cf = 0; cf < 3; ++cf) {
      bf16x8 bfr = *(const bf16x8*)(WbT + (size_t)(48 * w + 16 * cf + l15) * Cn + ks * 32 + quad * 8);
      acc[cf] = MFMA(a, bfr, acc[cf]);
    }
  }
  #pragma unroll
  for (int cf = 0; cf < 3; ++cf) {
    int cbase = 48 * w + 16 * cf, c = cbase + l15;
    #pragma unroll
    for (int r = 0; r < 4; ++r) {
      int row = t0 + quad * 4 + r;
      short val = f2bf(acc[cf][r]);
      if (cbase < 64)       qb[(size_t)row * Hn + c] = val;
      else if (cbase < 128) kb[(size_t)row * Hn + (c - 64)] = val;
      else                  vtile[c - 128][quad * 4 + r] = val;
    }
  }
  __syncthreads();
  const int b = t0 >> 11, t0l = t0 & 2047;
  int h = tid >> 2, tseg = (tid & 3) * 4;
  *(short4*)(vT + ((size_t)(b * Hn + h)) * Tn + t0l + tseg) =
      *(const short4*)(&vtile[h][tseg]);
}

// ---------------- K2: balanced column exp-sums -> pL partials, plus E cache -
// Pair (colchunk j: 32-j t-groups) with (colchunk 31-j: j+1 t-groups) = 33.
// unit = ((b*16 + j)*8 + u): u-th eighth of the pair's 33 t-group list.
// Stores E[b][t][s] = exp(score*scale) (0 above diagonal) as bf16, and
// pL[unit][slot][64] partial column sums (slot 0 = chunk j, 1 = chunk 31-j),
// both slots ALWAYS written (zeros if unit has no work there) -> no memset.
__global__ __launch_bounds__(256) void colstats_kernel(
    const short* __restrict__ qb, const short* __restrict__ kb,
    float* __restrict__ pL, short* __restrict__ Eb) {
  const int unit = blockIdx.x;
  const int b = unit >> 7, rem = unit & 127;
  const int j = rem >> 3, u = rem & 7;
  const int lo = (u * 33) >> 3, hi = ((u + 1) * 33) >> 3;  // 4 or 5 entries
  const int big = 32 - j;
  const int tid = threadIdx.x, w = tid >> 6, l15 = tid & 15, quad = (tid & 63) >> 4;
  const size_t Ebase = (size_t)b * Tn * Tn;
  __shared__ float redl[64][17];

  auto run = [&](const int i, const int k0, const int k1, const int slot) {
    const int s0 = i << 6;
    float l[4] = {0.f, 0.f, 0.f, 0.f};
    if (k0 < k1) {                         // block-uniform: barrier-safe
      bf16x8 bk[8];
      #pragma unroll
      for (int nf = 0; nf < 4; ++nf) {
        const size_t krow = (size_t)(b * Tn + s0 + 16 * nf + l15) * Hn;
        bk[2 * nf]     = *(const bf16x8*)(kb + krow + quad * 8);
        bk[2 * nf + 1] = *(const bf16x8*)(kb + krow + 32 + quad * 8);
      }
      auto cload = [&](bf16x8& A0, bf16x8& A1, int k) {
        size_t ar = (size_t)(b * Tn + ((i + k) << 6) + 16 * w + l15) * Hn;
        A0 = *(const bf16x8*)(qb + ar + quad * 8);
        A1 = *(const bf16x8*)(qb + ar + 32 + quad * 8);
      };
      auto ccomp = [&](bf16x8 A0, bf16x8 A1, int k) {
        f32x4 sc[4] = {};
        #pragma unroll
        for (int nf = 0; nf < 4; ++nf) {
          sc[nf] = MFMA(A0, bk[2 * nf], sc[nf]);
          sc[nf] = MFMA(A1, bk[2 * nf + 1], sc[nf]);
        }
        const bool diag = (k == 0);
        const int tb = ((i + k) << 6) + 16 * w + quad * 4;
        #pragma unroll
        for (int nf = 0; nf < 4; ++nf) {
          int s = s0 + 16 * nf + l15;
          #pragma unroll
          for (int r = 0; r < 4; ++r) {
            float v = sc[nf][r] * SCALE;
            if (diag && (tb + r) < s) v = -INFINITY;  // exp(-inf) = 0
            float ev = __expf(v);
            l[nf] += ev;
            Eb[Ebase + (size_t)(tb + r) * Tn + s] = f2bf(ev);  // fire-and-forget
          }
        }
      };
      bf16x8 a0A, a1A, a0B, a1B;
      cload(a0A, a1A, k0);
      int k = k0;
      while (k + 1 < k1) {
        cload(a0B, a1B, k + 1);
        ccomp(a0A, a1A, k);
        if (k + 2 < k1) cload(a0A, a1A, k + 2);
        ccomp(a0B, a1B, k + 1);
        k += 2;
      }
      if (k < k1) ccomp(a0A, a1A, k);
    }
    __syncthreads();  // protect redl reuse across phases
    #pragma unroll
    for (int nf = 0; nf < 4; ++nf) redl[16 * nf + l15][w * 4 + quad] = l[nf];
    __syncthreads();
    if (tid < 64) {
      float ls = 0.f;
      #pragma unroll
      for (int q2 = 0; q2 < 16; ++q2) ls += redl[tid][q2];
      pL[unit * 128 + slot * 64 + tid] = ls;
    }
  };
  run(j, lo, min(hi, big), 0);                       // big member: colchunk j
  run(31 - j, max(lo, big) - big, hi - big, 1);      // small: colchunk 31-j
}

// ---------------- K3: vS[h][s] = vT[h][s] / L[s]; also zeroes out -----------
// L[s] = sum over the 8 units of column-chunk s's pair (slot by membership).
__global__ __launch_bounds__(256) void vhat_kernel(
    const short* __restrict__ vT, const float* __restrict__ pL,
    short* __restrict__ vS, float* __restrict__ outz) {
  int gid = blockIdx.x * 256 + threadIdx.x;  // 131072 threads x 8 elems
  size_t base = (size_t)gid * 8;
  int b = (int)(base >> 17), s = (int)(base & 2047);
  int i = s >> 6, c = s & 63;
  int j2 = (i < 16) ? i : 31 - i;
  int slot = (i < 16) ? 0 : 1;
  const float* pp = pL + (size_t)((b * 16 + j2) * 8) * 128 + slot * 64 + c;
  float L0x = 0.f, L0y = 0.f, L0z = 0.f, L0w = 0.f;
  float L1x = 0.f, L1y = 0.f, L1z = 0.f, L1w = 0.f;
  #pragma unroll
  for (int u = 0; u < 8; ++u) {
    float4 p0 = *(const float4*)(pp + u * 128);
    float4 p1 = *(const float4*)(pp + u * 128 + 4);
    L0x += p0.x; L0y += p0.y; L0z += p0.z; L0w += p0.w;
    L1x += p1.x; L1y += p1.y; L1z += p1.z; L1w += p1.w;
  }
  short4 v0 = *(const short4*)(vT + base);
  short4 v1 = *(const short4*)(vT + base + 4);
  short4 r0, r1;
  r0.x = f2bf(bf2f(v0.x) / L0x); r0.y = f2bf(bf2f(v0.y) / L0y);
  r0.z = f2bf(bf2f(v0.z) / L0z); r0.w = f2bf(bf2f(v0.w) / L0w);
  r1.x = f2bf(bf2f(v1.x) / L1x); r1.y = f2bf(bf2f(v1.y) / L1y);
  r1.z = f2bf(bf2f(v1.z) / L1z); r1.w = f2bf(bf2f(v1.w) / L1w);
  *(short4*)(vS + base) = r0;
  *(short4*)(vS + base + 4) = r1;
  float4 z = {0.f, 0.f, 0.f, 0.f};   // fold out-memset: same 1M-float extent
  *(float4*)(outz + base) = z;
  *(float4*)(outz + base + 4) = z;
}

// ---------------- K4: out = E_tri . vS^T, pair-balanced, atomic flush -------
// Pair (tile 31-j: 32-j chunks) with (tile j: j+1 chunks) = 33 chunks.
// unit = ((b*16 + j)*8 + u): u-th eighth of the pair's chunk list.
// Pure GEMM chunks: 10 loads + 8 MFMA, A/B register dbuf, no exp/LDS/barriers.
__global__ __launch_bounds__(256) void outg_kernel(
    const short* __restrict__ Eb, const short* __restrict__ vS,
    float* __restrict__ out) {
  const int unit = blockIdx.x;
  const int b = unit >> 7, rem = unit & 127;
  const int j = rem >> 3, u = rem & 7;
  const int lo = (u * 33) >> 3, hi = ((u + 1) * 33) >> 3;  // 4 or 5 chunks
  const int big = 32 - j;                                   // chunks in big member
  const int tid = threadIdx.x, w = tid >> 6, l15 = tid & 15, quad = (tid & 63) >> 4;
  const size_t Bbase = (size_t)b * Hn * Tn;

  auto run = [&](const int tile, const int k0, const int k1) {
    if (k0 >= k1) return;
    const int tbase = (tile << 6) + 16 * w;
    const size_t Abase = (size_t)b * Tn * Tn + (size_t)(tbase + l15) * Tn;
    f32x4 acc[4] = {};
    bf16x8 aA[2], bA[8], aB[2], bB[8];
    auto load = [&](bf16x8 (&A)[2], bf16x8 (&Bf)[8], int ch) {
      const int s0 = ch << 6;
      A[0] = *(const bf16x8*)(Eb + Abase + s0 + quad * 8);
      A[1] = *(const bf16x8*)(Eb + Abase + s0 + 32 + quad * 8);
      #pragma unroll
      for (int nf = 0; nf < 4; ++nf) {
        const size_t br = Bbase + (size_t)(16 * nf + l15) * Tn + s0;
        Bf[2 * nf]     = *(const bf16x8*)(vS + br + quad * 8);
        Bf[2 * nf + 1] = *(const bf16x8*)(vS + br + 32 + quad * 8);
      }
    };
    auto comp = [&](bf16x8 (&A)[2], bf16x8 (&Bf)[8]) {
      #pragma unroll
      for (int nf = 0; nf < 4; ++nf) {
        acc[nf] = MFMA(A[0], Bf[2 * nf], acc[nf]);
        acc[nf] = MFMA(A[1], Bf[2 * nf + 1], acc[nf]);
      }
    };
    load(aA, bA, k0);
    int ch = k0;
    while (ch + 1 < k1) {  // manual 2x unroll: A/B buffers, no register copies
      load(aB, bB, ch + 1);
      comp(aA, bA);
      if (ch + 2 < k1) load(aA, bA, ch + 2);
      comp(aB, bB);
      ch += 2;
    }
    if (ch < k1) comp(aA, bA);
    #pragma unroll
    for (int nf = 0; nf < 4; ++nf)
      #pragma unroll
      for (int r = 0; r < 4; ++r)
        atomicAdd(&out[(size_t)(b * Tn + tbase + quad * 4 + r) * Hn + 16 * nf + l15],
                  acc[nf][r]);
  };
  run(31 - j, lo, min(hi, big));              // big member: tile 31-j
  run(j, max(lo, big) - big, hi - big);       // small member: tile j
}

extern "C" void kernel_launch(void* const* d_in, const int* in_sizes, int n_in,
                              void* d_out, int out_size, void* d_ws, size_t ws_size,
                              hipStream_t stream) {
  const float* x  = (const float*)d_in[0];
  const float* Wq = (const float*)d_in[1];
  const float* Wk = (const float*)d_in[2];
  const float* Wv = (const float*)d_in[3];
  char* ws = (char*)d_ws;                          // needs ~80 MB
  short* qb   = (short*)(ws);                      // 2 MB (T,H)
  short* kb   = (short*)(ws + 2097152);            // 2 MB (T,H)
  short* vT   = (short*)(ws + 4194304);            // 2 MB (H,T)
  short* vS   = (short*)(ws + 6291456);            // 2 MB (H,T) v/L
  short* WbT  = (short*)(ws + 8388608);            // 144 KB
  float* pL   = (float*)(ws + 8536064);            // 512 KB unit partial sums
  short* Eb   = (short*)(ws + 16777216);           // 64 MB (B,T,T) bf16
  float* outp = (float*)d_out;

  hipLaunchKernelGGL(wconv_kernel, dim3(288), dim3(256), 0, stream, Wq, Wk, Wv, WbT);
  hipLaunchKernelGGL(proj_kernel, dim3(Bn * Tn / 16), dim3(256), 0, stream, x, WbT, qb, kb, vT);
  hipLaunchKernelGGL(colstats_kernel, dim3(1024), dim3(256), 0, stream, qb, kb, pL, Eb);
  hipLaunchKernelGGL(vhat_kernel, dim3(512), dim3(256), 0, stream, vT, pL, vS, outp);
  hipLaunchKernelGGL(outg_kernel, dim3(1024), dim3(256), 0, stream, Eb, vS, outp);
}

// Round 12
// 144.423 us; speedup vs baseline: 1.1038x; 1.0023x over previous
//
#include <hip/hip_runtime.h>
#include <hip/hip_bf16.h>
#include <math.h>

#define Bn 8
#define Tn 2048
#define Cn 384
#define Hn 64
#define SCALE 0.051031036307982884f   // 384^-0.5
#define SCALE2 0.07362240熙f_IGNORE   // placeholder (real def below)
#undef SCALE2
#define SCALE2 0.07362241f            // SCALE * log2(e): exp(x*SCALE)=2^(x*SCALE2)

using bf16x8 = __attribute__((ext_vector_type(8))) short;  // 8 bf16 = 4 VGPRs
using f32x4  = __attribute__((ext_vector_type(4))) float;

#define MFMA(a, b, c) __builtin_amdgcn_mfma_f32_16x16x32_bf16((a), (b), (c), 0, 0, 0)

static __device__ __forceinline__ short f2bf(float f) {  // RNE fp32->bf16
  unsigned u = __float_as_uint(f);
  u += 0x7fffu + ((u >> 16) & 1u);
  return (short)(u >> 16);
}
static __device__ __forceinline__ float bf2f(short s) {
  return __uint_as_float(((unsigned)(unsigned short)s) << 16);
}
static __device__ __forceinline__ float fexp2(float x) {  // v_exp_f32 (base-2)
#if __has_builtin(__builtin_amdgcn_exp2f)
  return __builtin_amdgcn_exp2f(x);
#else
  return exp2f(x);
#endif
}

// ---------------- K0: W -> WbT (192 x 384) bf16, row n = output col ---------
__global__ __launch_bounds__(256) void wconv_kernel(
    const float* __restrict__ Wq, const float* __restrict__ Wk,
    const float* __restrict__ Wv, short* __restrict__ WbT) {
  int idx = blockIdx.x * 256 + threadIdx.x;  // n*384 + k, 73728 total
  int n = idx / 384, k = idx - n * 384;
  const float* W = (n < 64) ? Wq : (n < 128) ? Wk : Wv;
  WbT[idx] = f2bf(W[k * 64 + (n & 63)]);
}

// ---------------- K1: proj GEMM, 16-row tiles (1024 blocks, 4/CU) -----------
__global__ __launch_bounds__(256) void proj_kernel(
    const float* __restrict__ x, const short* __restrict__ WbT,
    short* __restrict__ qb, short* __restrict__ kb, short* __restrict__ vT) {
  __shared__ short xs[16][392];    // stride 392: banks 2-way (free)
  __shared__ short vtile[64][20];  // v-tile transpose bounce
  const int tid = threadIdx.x;
  const int t0 = blockIdx.x * 16;  // global row (b*2048 + t)
  const float* xb = x + (size_t)t0 * Cn;
  #pragma unroll
  for (int i = 0; i < 6; ++i) {
    int j = tid + i * 256;  // float4 index, 1536 total
    int row = j / 96, colv = (j - row * 96) * 4;
    float4 v = *(const float4*)(xb + row * Cn + colv);
    short4 s4; s4.x = f2bf(v.x); s4.y = f2bf(v.y); s4.z = f2bf(v.z); s4.w = f2bf(v.w);
    *(short4*)(&xs[row][colv]) = s4;
  }
  __syncthreads();
  const int w = tid >> 6, l15 = tid & 15, quad = (tid & 63) >> 4;
  f32x4 acc[3] = {};
  for (int ks = 0; ks < 12; ++ks) {
    bf16x8 a = *(const bf16x8*)(&xs[l15][ks * 32 + quad * 8]);
    #pragma unroll
    for (int cf = 0; cf < 3; ++cf) {
      bf16x8 bfr = *(const bf16x8*)(WbT + (size_t)(48 * w + 16 * cf + l15) * Cn + ks * 32 + quad * 8);
      acc[cf] = MFMA(a, bfr, acc[cf]);
    }
  }
  #pragma unroll
  for (int cf = 0; cf < 3; ++cf) {
    int cbase = 48 * w + 16 * cf, c = cbase + l15;
    #pragma unroll
    for (int r = 0; r < 4; ++r) {
      int row = t0 + quad * 4 + r;
      short val = f2bf(acc[cf][r]);
      if (cbase < 64)       qb[(size_t)row * Hn + c] = val;
      else if (cbase < 128) kb[(size_t)row * Hn + (c - 64)] = val;
      else                  vtile[c - 128][quad * 4 + r] = val;
    }
  }
  __syncthreads();
  const int b = t0 >> 11, t0l = t0 & 2047;
  int h = tid >> 2, tseg = (tid & 3) * 4;
  *(short4*)(vT + ((size_t)(b * Hn + h)) * Tn + t0l + tseg) =
      *(const short4*)(&vtile[h][tseg]);
}

// ---------------- K2: balanced column exp-sums -> pL partials, plus E cache -
// Pair (colchunk j: 32-j t-groups) with (colchunk 31-j: j+1 t-groups) = 33.
// unit = ((b*16 + j)*8 + u): u-th eighth of the pair's 33 t-group list.
// 3-deep A-frag prefetch (A/B/C buffers): 2 chunk-loads in flight per comp.
__global__ __launch_bounds__(256) void colstats_kernel(
    const short* __restrict__ qb, const short* __restrict__ kb,
    float* __restrict__ pL, short* __restrict__ Eb) {
  const int unit = blockIdx.x;
  const int b = unit >> 7, rem = unit & 127;
  const int j = rem >> 3, u = rem & 7;
  const int lo = (u * 33) >> 3, hi = ((u + 1) * 33) >> 3;  // 4 or 5 entries
  const int big = 32 - j;
  const int tid = threadIdx.x, w = tid >> 6, l15 = tid & 15, quad = (tid & 63) >> 4;
  const size_t Ebase = (size_t)b * Tn * Tn;
  __shared__ float redl[64][17];

  auto run = [&](const int i, const int k0, const int k1, const int slot) {
    const int s0 = i << 6;
    float l[4] = {0.f, 0.f, 0.f, 0.f};
    const int n = k1 - k0;
    if (n > 0) {                           // block-uniform: barrier-safe
      bf16x8 bk[8];
      #pragma unroll
      for (int nf = 0; nf < 4; ++nf) {
        const size_t krow = (size_t)(b * Tn + s0 + 16 * nf + l15) * Hn;
        bk[2 * nf]     = *(const bf16x8*)(kb + krow + quad * 8);
        bk[2 * nf + 1] = *(const bf16x8*)(kb + krow + 32 + quad * 8);
      }
      auto cload = [&](bf16x8& A0, bf16x8& A1, int k) {
        size_t ar = (size_t)(b * Tn + ((i + k) << 6) + 16 * w + l15) * Hn;
        A0 = *(const bf16x8*)(qb + ar + quad * 8);
        A1 = *(const bf16x8*)(qb + ar + 32 + quad * 8);
      };
      auto ccomp = [&](bf16x8 A0, bf16x8 A1, int k) {
        f32x4 sc[4] = {};
        #pragma unroll
        for (int nf = 0; nf < 4; ++nf) {
          sc[nf] = MFMA(A0, bk[2 * nf], sc[nf]);
          sc[nf] = MFMA(A1, bk[2 * nf + 1], sc[nf]);
        }
        const bool diag = (k == 0);
        const int tb = ((i + k) << 6) + 16 * w + quad * 4;
        #pragma unroll
        for (int nf = 0; nf < 4; ++nf) {
          int s = s0 + 16 * nf + l15;
          #pragma unroll
          for (int r = 0; r < 4; ++r) {
            float v = sc[nf][r] * SCALE2;            // exp2-domain score
            if (diag && (tb + r) < s) v = -INFINITY; // exp2(-inf) = 0
            float ev = fexp2(v);
            l[nf] += ev;
            Eb[Ebase + (size_t)(tb + r) * Tn + s] = f2bf(ev);  // fire-and-forget
          }
        }
      };
      bf16x8 a0A, a1A, a0B, a1B, a0C, a1C;
      cload(a0A, a1A, k0);
      if (n > 1) cload(a0B, a1B, k0 + 1);
      if (n > 2) cload(a0C, a1C, k0 + 2);
      int k = k0;
      while (k + 3 < k1) {  // 3x unrolled steady state, 2 loads in flight
        ccomp(a0A, a1A, k);     cload(a0A, a1A, k + 3);
        ccomp(a0B, a1B, k + 1); if (k + 4 < k1) cload(a0B, a1B, k + 4);
        ccomp(a0C, a1C, k + 2); if (k + 5 < k1) cload(a0C, a1C, k + 5);
        k += 3;
      }
      const int rem2 = k1 - k;
      if (rem2 > 0) ccomp(a0A, a1A, k);
      if (rem2 > 1) ccomp(a0B, a1B, k + 1);
      if (rem2 > 2) ccomp(a0C, a1C, k + 2);
    }
    __syncthreads();  // protect redl reuse across phases
    #pragma unroll
    for (int nf = 0; nf < 4; ++nf) redl[16 * nf + l15][w * 4 + quad] = l[nf];
    __syncthreads();
    if (tid < 64) {
      float ls = 0.f;
      #pragma unroll
      for (int q2 = 0; q2 < 16; ++q2) ls += redl[tid][q2];
      pL[unit * 128 + slot * 64 + tid] = ls;
    }
  };
  run(j, lo, min(hi, big), 0);                       // big member: colchunk j
  run(31 - j, max(lo, big) - big, hi - big, 1);      // small: colchunk 31-j
}

// ---------------- K3: vS[h][s] = vT[h][s] / L[s]; also zeroes out -----------
// L[s] = sum over the 8 units of column-chunk s's pair (slot by membership).
__global__ __launch_bounds__(256) void vhat_kernel(
    const short* __restrict__ vT, const float* __restrict__ pL,
    short* __restrict__ vS, float* __restrict__ outz) {
  int gid = blockIdx.x * 256 + threadIdx.x;  // 131072 threads x 8 elems
  size_t base = (size_t)gid * 8;
  int b = (int)(base >> 17), s = (int)(base & 2047);
  int i = s >> 6, c = s & 63;
  int j2 = (i < 16) ? i : 31 - i;
  int slot = (i < 16) ? 0 : 1;
  const float* pp = pL + (size_t)((b * 16 + j2) * 8) * 128 + slot * 64 + c;
  float L0x = 0.f, L0y = 0.f, L0z = 0.f, L0w = 0.f;
  float L1x = 0.f, L1y = 0.f, L1z = 0.f, L1w = 0.f;
  #pragma unroll
  for (int u = 0; u < 8; ++u) {
    float4 p0 = *(const float4*)(pp + u * 128);
    float4 p1 = *(const float4*)(pp + u * 128 + 4);
    L0x += p0.x; L0y += p0.y; L0z += p0.z; L0w += p0.w;
    L1x += p1.x; L1y += p1.y; L1z += p1.z; L1w += p1.w;
  }
  short4 v0 = *(const short4*)(vT + base);
  short4 v1 = *(const short4*)(vT + base + 4);
  short4 r0, r1;
  r0.x = f2bf(bf2f(v0.x) / L0x); r0.y = f2bf(bf2f(v0.y) / L0y);
  r0.z = f2bf(bf2f(v0.z) / L0z); r0.w = f2bf(bf2f(v0.w) / L0w);
  r1.x = f2bf(bf2f(v1.x) / L1x); r1.y = f2bf(bf2f(v1.y) / L1y);
  r1.z = f2bf(bf2f(v1.z) / L1z); r1.w = f2bf(bf2f(v1.w) / L1w);
  *(short4*)(vS + base) = r0;
  *(short4*)(vS + base + 4) = r1;
  float4 z = {0.f, 0.f, 0.f, 0.f};   // fold out-memset: same 1M-float extent
  *(float4*)(outz + base) = z;
  *(float4*)(outz + base + 4) = z;
}

// ---------------- K4: out = E_tri . vS^T, pair-balanced, atomic flush -------
// Pair (tile 31-j: 32-j chunks) with (tile j: j+1 chunks) = 33 chunks.
// unit = ((b*16 + j)*8 + u): u-th eighth of the pair's chunk list.
// Pure GEMM chunks: 10 loads + 8 MFMA, A/B register dbuf, no exp/LDS/barriers.
__global__ __launch_bounds__(256) void outg_kernel(
    const short* __restrict__ Eb, const short* __restrict__ vS,
    float* __restrict__ out) {
  const int unit = blockIdx.x;
  const int b = unit >> 7, rem = unit & 127;
  const int j = rem >> 3, u = rem & 7;
  const int lo = (u * 33) >> 3, hi = ((u + 1) * 33) >> 3;  // 4 or 5 chunks
  const int big = 32 - j;                                   // chunks in big member
  const int tid = threadIdx.x, w = tid >> 6, l15 = tid & 15, quad = (tid & 63) >> 4;
  const size_t Bbase = (size_t)b * Hn * Tn;

  auto run = [&](const int tile, const int k0, const int k1) {
    if (k0 >= k1) return;
    const int tbase = (tile << 6) + 16 * w;
    const size_t Abase = (size_t)b * Tn * Tn + (size_t)(tbase + l15) * Tn;
    f32x4 acc[4] = {};
    bf16x8 aA[2], bA[8], aB[2], bB[8];
    auto load = [&](bf16x8 (&A)[2], bf16x8 (&Bf)[8], int ch) {
      const int s0 = ch << 6;
      A[0] = *(const bf16x8*)(Eb + Abase + s0 + quad * 8);
      A[1] = *(const bf16x8*)(Eb + Abase + s0 + 32 + quad * 8);
      #pragma unroll
      for (int nf = 0; nf < 4; ++nf) {
        const size_t br = Bbase + (size_t)(16 * nf + l15) * Tn + s0;
        Bf[2 * nf]     = *(const bf16x8*)(vS + br + quad * 8);
        Bf[2 * nf + 1] = *(const bf16x8*)(vS + br + 32 + quad * 8);
      }
    };
    auto comp = [&](bf16x8 (&A)[2], bf16x8 (&Bf)[8]) {
      #pragma unroll
      for (int nf = 0; nf < 4; ++nf) {
        acc[nf] = MFMA(A[0], Bf[2 * nf], acc[nf]);
        acc[nf] = MFMA(A[1], Bf[2 * nf + 1], acc[nf]);
      }
    };
    load(aA, bA, k0);
    int ch = k0;
    while (ch + 1 < k1) {  // manual 2x unroll: A/B buffers, no register copies
      load(aB, bB, ch + 1);
      comp(aA, bA);
      if (ch + 2 < k1) load(aA, bA, ch + 2);
      comp(aB, bB);
      ch += 2;
    }
    if (ch < k1) comp(aA, bA);
    #pragma unroll
    for (int nf = 0; nf < 4; ++nf)
      #pragma unroll
      for (int r = 0; r < 4; ++r)
        atomicAdd(&out[(size_t)(b * Tn + tbase + quad * 4 + r) * Hn + 16 * nf + l15],
                  acc[nf][r]);
  };
  run(31 - j, lo, min(hi, big));              // big member: tile 31-j
  run(j, max(lo, big) - big, hi - big);       // small member: tile j
}

extern "C" void kernel_launch(void* const* d_in, const int* in_sizes, int n_in,
                              void* d_out, int out_size, void* d_ws, size_t ws_size,
                              hipStream_t stream) {
  const float* x  = (const float*)d_in[0];
  const float* Wq = (const float*)d_in[1];
  const float* Wk = (const float*)d_in[2];
  const float* Wv = (const float*)d_in[3];
  char* ws = (char*)d_ws;                          // needs ~80 MB
  short* qb   = (short*)(ws);                      // 2 MB (T,H)
  short* kb   = (short*)(ws + 2097152);            // 2 MB (T,H)
  short* vT   = (short*)(ws + 4194304);            // 2 MB (H,T)
  short* vS   = (short*)(ws + 6291456);            // 2 MB (H,T) v/L
  short* WbT  = (short*)(ws + 8388608);            // 144 KB
  float* pL   = (float*)(ws + 8536064);            // 512 KB unit partial sums
  short* Eb   = (short*)(ws + 16777216);           // 64 MB (B,T,T) bf16
  float* outp = (float*)d_out;

  hipLaunchKernelGGL(wconv_kernel, dim3(288), dim3(256), 0, stream, Wq, Wk, Wv, WbT);
  hipLaunchKernelGGL(proj_kernel, dim3(Bn * Tn / 16), dim3(256), 0, stream, x, WbT, qb, kb, vT);
  hipLaunchKernelGGL(colstats_kernel, dim3(1024), dim3(256), 0, stream, qb, kb, pL, Eb);
  hipLaunchKernelGGL(vhat_kernel, dim3(512), dim3(256), 0, stream, vT, pL, vS, outp);
  hipLaunchKernelGGL(outg_kernel, dim3(1024), dim3(256), 0, stream, Eb, vS, outp);
}